// Round 2
// baseline (292.785 us; speedup 1.0000x reference)
//
#include <hip/hip_runtime.h>

// Integrator: y = cumsum(x, axis=-1) over (8,4,1048576) fp32.
// Single-pass decoupled-lookback scan (StreamScan):
//   init kernel zeroes descriptors + ticket
//   scan kernel: ticketed block id -> load tile -> block scan ->
//     publish aggregate -> wave-parallel lookback -> publish inclusive ->
//     add offset -> store.  Traffic: read x once + write y once (268 MB).

constexpr int ROWS           = 32;        // B*C = 8*4
constexpr int T_LEN          = 1048576;
constexpr int THREADS        = 256;
constexpr int PER_THREAD     = 32;        // contiguous floats per thread
constexpr int TILE           = THREADS * PER_THREAD;   // 8192
constexpr int BLOCKS_PER_ROW = T_LEN / TILE;           // 128
constexpr int TOTAL_BLOCKS   = ROWS * BLOCKS_PER_ROW;  // 4096

// descriptor: high 32 = state (0 invalid, 1 aggregate, 2 inclusive-prefix),
//             low 32  = float bits of the value. One atomic word -> no
//             torn/stale reads across XCDs.

__global__ __launch_bounds__(THREADS) void integ_init(
    unsigned long long* __restrict__ desc, unsigned int* __restrict__ ticket) {
  const int i = blockIdx.x * blockDim.x + threadIdx.x;
  if (i < TOTAL_BLOCKS) desc[i] = 0ULL;
  if (i == 0) *ticket = 0u;
}

__global__ __launch_bounds__(THREADS) void integ_scan(
    const float* __restrict__ x, float* __restrict__ y,
    unsigned long long* __restrict__ desc, unsigned int* __restrict__ ticket) {
  __shared__ unsigned int s_bid;
  __shared__ float s_wsum[4];
  __shared__ float s_excl;

  const int t = threadIdx.x;
  if (t == 0) s_bid = atomicAdd(ticket, 1u);   // monotonic start order
  __syncthreads();
  const int bid  = (int)s_bid;
  const int row  = bid >> 7;                   // / BLOCKS_PER_ROW
  const int tile = bid & (BLOCKS_PER_ROW - 1);
  const size_t base = (size_t)row * T_LEN + (size_t)tile * TILE
                    + (size_t)t * PER_THREAD;

  // load 32 contiguous floats per thread
  const float4* p = (const float4*)(x + base);
  float v[PER_THREAD];
#pragma unroll
  for (int j = 0; j < PER_THREAD / 4; ++j) {
    float4 q = p[j];
    v[4 * j + 0] = q.x; v[4 * j + 1] = q.y; v[4 * j + 2] = q.z; v[4 * j + 3] = q.w;
  }

  // thread-local inclusive scan
#pragma unroll
  for (int i = 1; i < PER_THREAD; ++i) v[i] += v[i - 1];
  const float tsum = v[PER_THREAD - 1];

  // block scan of per-thread sums
  const int lane = t & 63;
  const int wid  = t >> 6;
  float s = tsum;
#pragma unroll
  for (int d = 1; d < 64; d <<= 1) {
    float n = __shfl_up(s, d, 64);
    if (lane >= d) s += n;
  }
  if (lane == 63) s_wsum[wid] = s;
  __syncthreads();
  float prev = 0.f, agg = 0.f;
#pragma unroll
  for (int w = 0; w < 4; ++w) {
    const float ws = s_wsum[w];
    agg += ws;
    if (w < wid) prev += ws;
  }
  const float ex = prev + s - tsum;            // exclusive prefix within tile

  // ---- decoupled lookback, wave 0 only (wave-uniform control flow) ----
  if (wid == 0) {
    if (tile == 0) {
      if (lane == 0) {
        __hip_atomic_store(&desc[bid],
            (2ULL << 32) | (unsigned long long)__float_as_uint(agg),
            __ATOMIC_RELAXED, __HIP_MEMORY_SCOPE_AGENT);
        s_excl = 0.f;
      }
    } else {
      if (lane == 0)
        __hip_atomic_store(&desc[bid],
            (1ULL << 32) | (unsigned long long)__float_as_uint(agg),
            __ATOMIC_RELAXED, __HIP_MEMORY_SCOPE_AGENT);

      float excl   = 0.f;
      int remaining = tile;    // predecessors in this row
      int winEnd    = bid;     // window = [winEnd-nwin, winEnd)
      while (remaining > 0) {
        const int  nwin   = remaining < 64 ? remaining : 64;
        const bool active = lane < nwin;
        const int  j      = winEnd - 1 - lane;   // lane 0 = closest pred
        unsigned long long d = 0ULL;
        int lp;                                   // lane of closest P (or nwin)
        while (true) {
          if (active)
            d = __hip_atomic_load(&desc[j], __ATOMIC_RELAXED,
                                  __HIP_MEMORY_SCOPE_AGENT);
          const unsigned st = (unsigned)(d >> 32);
          const unsigned long long pm = __ballot(active && st == 2u);
          const unsigned long long zm = __ballot(active && st == 0u);
          if (pm) {
            lp = (int)(__ffsll((unsigned long long)pm) - 1);
            const unsigned long long need =
                (lp == 0) ? 0ULL : ((1ULL << lp) - 1ULL);
            if ((zm & need) == 0ULL) break;   // all closer preds have >= A
          } else if (zm == 0ULL) {
            lp = nwin;                        // whole window is aggregates
            break;
          }
        }
        // lanes < lp contribute aggregates, lane lp (if P) its inclusive
        float c = 0.f;
        if (active && lane <= lp)
          c = __uint_as_float((unsigned)(d & 0xffffffffULL));
#pragma unroll
        for (int o = 32; o > 0; o >>= 1) c += __shfl_xor(c, o, 64);
        excl += c;
        if (lp < nwin) { remaining = 0; }
        else           { remaining -= nwin; winEnd -= nwin; }
      }

      if (lane == 0) {
        __hip_atomic_store(&desc[bid],
            (2ULL << 32) | (unsigned long long)__float_as_uint(excl + agg),
            __ATOMIC_RELAXED, __HIP_MEMORY_SCOPE_AGENT);
        s_excl = excl;
      }
    }
  }
  __syncthreads();

  const float off = s_excl + ex;
#pragma unroll
  for (int i = 0; i < PER_THREAD; ++i) v[i] += off;

  float4* q = (float4*)(y + base);
#pragma unroll
  for (int j = 0; j < PER_THREAD / 4; ++j) {
    float4 o;
    o.x = v[4 * j + 0]; o.y = v[4 * j + 1];
    o.z = v[4 * j + 2]; o.w = v[4 * j + 3];
    q[j] = o;
  }
}

extern "C" void kernel_launch(void* const* d_in, const int* in_sizes, int n_in,
                              void* d_out, int out_size, void* d_ws, size_t ws_size,
                              hipStream_t stream) {
  const float* x = (const float*)d_in[0];
  float* y = (float*)d_out;
  unsigned long long* desc = (unsigned long long*)d_ws;          // 4096 * 8 B
  unsigned int* ticket = (unsigned int*)(desc + TOTAL_BLOCKS);   // 4 B

  integ_init<<<(TOTAL_BLOCKS + THREADS - 1) / THREADS, THREADS, 0, stream>>>(desc, ticket);
  integ_scan<<<TOTAL_BLOCKS, THREADS, 0, stream>>>(x, y, desc, ticket);
}

// Round 3
// 252.176 us; speedup vs baseline: 1.1610x; 1.1610x over previous
//
#include <hip/hip_runtime.h>

// Integrator: y = cumsum(x, axis=-1) over (8,4,1048576) fp32.
// Two-kernel reduce-then-scan:
//   A: per-tile sums (read x once, coalesced float4)
//   B: each block sums its <=255 predecessor tile-sums directly (part[] is
//      32 KB, L2-hot), local+block scan of its tile (x re-read hits L3),
//      add offset, write y. No phase-2 dispatch, no lookback, no init.

constexpr int ROWS           = 32;        // B*C = 8*4
constexpr int T_LEN          = 1048576;
constexpr int THREADS        = 256;
constexpr int PER_THREAD     = 16;        // contiguous floats per thread in B
constexpr int TILE           = THREADS * PER_THREAD;   // 4096
constexpr int BLOCKS_PER_ROW = T_LEN / TILE;           // 256
constexpr int TOTAL_BLOCKS   = ROWS * BLOCKS_PER_ROW;  // 8192

// ---------------- A: per-tile sums ----------------
__global__ __launch_bounds__(THREADS) void integ_reduce(
    const float* __restrict__ x, float* __restrict__ part) {
  const int blk = blockIdx.x;
  const size_t base = (size_t)blk * TILE;
  const float4* p = (const float4*)(x + base);
  const int t = threadIdx.x;
  const int lane = t & 63;
  const int wid  = t >> 6;

  float s = 0.f;
#pragma unroll
  for (int j = 0; j < TILE / 4 / THREADS; ++j) {   // 4 dense float4 sweeps
    float4 v = p[j * THREADS + t];
    s += (v.x + v.y) + (v.z + v.w);
  }
#pragma unroll
  for (int d = 32; d > 0; d >>= 1) s += __shfl_down(s, d, 64);

  __shared__ float wsum[4];
  if (lane == 0) wsum[wid] = s;
  __syncthreads();
  if (t == 0) part[blk] = (wsum[0] + wsum[1]) + (wsum[2] + wsum[3]);
}

// ---------------- B: offset + local scan + write ----------------
__global__ __launch_bounds__(THREADS) void integ_scan(
    const float* __restrict__ x, float* __restrict__ y,
    const float* __restrict__ part) {
  const int blk = blockIdx.x;
  const int row = blk >> 8;                // / BLOCKS_PER_ROW
  const int tb  = blk & (BLOCKS_PER_ROW - 1);
  const int t = threadIdx.x;
  const int lane = t & 63;
  const int wid  = t >> 6;

  __shared__ float s_pred[4];    // per-wave predecessor partial sums
  __shared__ float s_wscan[4];   // per-wave scan totals

  // 1) predecessor tile-sum: thread t owns part[row*256 + t] if t < tb
  float ps = (t < tb) ? part[(row << 8) + t] : 0.f;
#pragma unroll
  for (int o = 32; o > 0; o >>= 1) ps += __shfl_xor(ps, o, 64);
  if (lane == 0) s_pred[wid] = ps;

  // 2) load tile: 16 contiguous floats per thread (issues early, long latency)
  const size_t base = (size_t)blk * TILE + (size_t)t * PER_THREAD;
  const float4* p = (const float4*)(x + base);
  float v[PER_THREAD];
#pragma unroll
  for (int j = 0; j < PER_THREAD / 4; ++j) {
    float4 q = p[j];
    v[4 * j + 0] = q.x; v[4 * j + 1] = q.y; v[4 * j + 2] = q.z; v[4 * j + 3] = q.w;
  }

  // 3) thread-local inclusive scan
#pragma unroll
  for (int i = 1; i < PER_THREAD; ++i) v[i] += v[i - 1];
  const float tsum = v[PER_THREAD - 1];

  // 4) block scan of per-thread sums
  float s = tsum;
#pragma unroll
  for (int d = 1; d < 64; d <<= 1) {
    float n = __shfl_up(s, d, 64);
    if (lane >= d) s += n;
  }
  if (lane == 63) s_wscan[wid] = s;
  __syncthreads();   // single barrier: covers s_pred and s_wscan

  float off = (s_pred[0] + s_pred[1]) + (s_pred[2] + s_pred[3]);
  float prev = 0.f;
#pragma unroll
  for (int w = 0; w < 4; ++w) prev += (w < wid) ? s_wscan[w] : 0.f;
  off += prev + s - tsum;        // + exclusive prefix within tile

#pragma unroll
  for (int i = 0; i < PER_THREAD; ++i) v[i] += off;

  float4* q = (float4*)(y + base);
#pragma unroll
  for (int j = 0; j < PER_THREAD / 4; ++j) {
    float4 o;
    o.x = v[4 * j + 0]; o.y = v[4 * j + 1];
    o.z = v[4 * j + 2]; o.w = v[4 * j + 3];
    q[j] = o;
  }
}

extern "C" void kernel_launch(void* const* d_in, const int* in_sizes, int n_in,
                              void* d_out, int out_size, void* d_ws, size_t ws_size,
                              hipStream_t stream) {
  const float* x = (const float*)d_in[0];
  float* y = (float*)d_out;
  float* part = (float*)d_ws;   // TOTAL_BLOCKS floats = 32 KB

  integ_reduce<<<TOTAL_BLOCKS, THREADS, 0, stream>>>(x, part);
  integ_scan  <<<TOTAL_BLOCKS, THREADS, 0, stream>>>(x, y, part);
}